// Round 1
// baseline (882.980 us; speedup 1.0000x reference)
//
#include <hip/hip_runtime.h>
#include <math.h>

#define N_POS 4096
#define C_DIM 256
#define CQK_D 32

// ws layout (floats):
//   q_ws: [B][32][N]    at 0          (524288 floats)
//   k_ws: [B][32][N]    at 524288
//   v_ws: [B][256][N]   at 1048576    (4194304 floats)
//   o_ws: [B][N][256]   at 5242880    (4194304 floats)
// total = 9437184 floats = 36 MB

__global__ __launch_bounds__(256) void qkv_proj(
    const float* __restrict__ x,
    const float* __restrict__ Wq, const float* __restrict__ bq,
    const float* __restrict__ Wk, const float* __restrict__ bk,
    const float* __restrict__ Wv, const float* __restrict__ bv,
    float* __restrict__ q_ws, float* __restrict__ k_ws, float* __restrict__ v_ws)
{
    __shared__ float xs[128][64];   // [c_chunk][n] 32KB
    const int tid  = threadIdx.x;
    const int col  = tid & 63;      // n within tile
    const int rgrp = tid >> 6;      // 0..3
    const int nt = blockIdx.x;      // 0..63
    const int rt = blockIdx.y;      // 0..4 (row tile of 64 among 320 rows)
    const int b  = blockIdx.z;      // 0..3
    const int n0 = nt * 64;

    const float* W; const float* bias; float* outp; int row;
    if (rt == 0) {
        if (rgrp < 2) { W = Wq; bias = bq; outp = q_ws + b*CQK_D*N_POS; row = rgrp*16; }
        else          { W = Wk; bias = bk; outp = k_ws + b*CQK_D*N_POS; row = (rgrp-2)*16; }
    } else {
        W = Wv; bias = bv; outp = v_ws + b*C_DIM*N_POS; row = (rt-1)*64 + rgrp*16;
    }

    float acc[16];
    #pragma unroll
    for (int j = 0; j < 16; ++j) acc[j] = bias[row + j];

    for (int ch = 0; ch < 2; ++ch) {
        #pragma unroll
        for (int i = 0; i < 32; ++i) {
            const int cl = i*4 + rgrp;
            xs[cl][col] = x[((b*C_DIM) + ch*128 + cl)*N_POS + n0 + col];
        }
        __syncthreads();
        #pragma unroll 8
        for (int cc = 0; cc < 128; cc += 4) {
            const float xv0 = xs[cc+0][col], xv1 = xs[cc+1][col];
            const float xv2 = xs[cc+2][col], xv3 = xs[cc+3][col];
            #pragma unroll
            for (int j = 0; j < 16; ++j) {
                const float4 w = *reinterpret_cast<const float4*>(&W[(row+j)*C_DIM + ch*128 + cc]);
                acc[j] += w.x*xv0 + w.y*xv1 + w.z*xv2 + w.w*xv3;
            }
        }
        __syncthreads();
    }
    #pragma unroll
    for (int j = 0; j < 16; ++j)
        outp[(row+j)*N_POS + n0 + col] = acc[j];
}

__global__ __launch_bounds__(512) void flash_attn(
    const float* __restrict__ q_ws, const float* __restrict__ k_ws,
    const float* __restrict__ v_ws, float* __restrict__ o_ws)
{
    __shared__ float qs[32][64];     // [o][ql]
    __shared__ float ks[32][36];     // [kl][o] padded
    __shared__ float vs[32][257];    // [kl][c] padded
    __shared__ float ps[32][64];     // [kl][ql]
    __shared__ float pmaxs[8][64];
    __shared__ float psums[8][64];
    __shared__ float m_s[64], l_s[64], f_s[64];

    const int tid = threadIdx.x;
    const int qt  = blockIdx.x;      // 0..63
    const int b   = blockIdx.y;      // 0..3
    const int n0  = qt * 64;
    const int ql  = tid & 63;        // query lane / channel lane
    const int kg  = tid >> 6;        // 0..7

    const float* qb = q_ws + b*CQK_D*N_POS;
    const float* kb = k_ws + b*CQK_D*N_POS;
    const float* vb = v_ws + b*C_DIM*N_POS;

    #pragma unroll
    for (int i = 0; i < 4; ++i) {
        const int o = i*8 + kg;
        qs[o][ql] = qb[o*N_POS + n0 + ql];
    }
    if (tid < 64) { m_s[tid] = -INFINITY; l_s[tid] = 0.f; }
    __syncthreads();

    float qv[32];
    #pragma unroll
    for (int o = 0; o < 32; ++o) qv[o] = qs[o][ql];

    float oacc[4][8];   // [channel w][query j]
    #pragma unroll
    for (int w = 0; w < 4; ++w)
        #pragma unroll
        for (int j = 0; j < 8; ++j) oacc[w][j] = 0.f;

    const int c4 = ql;   // PV: channel lane (c4, c4+64, c4+128, c4+192)
    const int qg = kg;   // PV: query group (8 queries)

    for (int mt = 0; mt < 128; ++mt) {
        const int m0 = mt * 32;
        // K tile -> ks[kl][o] (transposed)
        if (tid < 256) {
            const int kl4 = tid & 7, o = tid >> 3;
            const float4 kv = *reinterpret_cast<const float4*>(&kb[o*N_POS + m0 + kl4*4]);
            ks[kl4*4+0][o] = kv.x; ks[kl4*4+1][o] = kv.y;
            ks[kl4*4+2][o] = kv.z; ks[kl4*4+3][o] = kv.w;
        }
        // V tile -> vs[kl][c]
        {
            const int kl4 = tid & 7, cbase = tid >> 3;  // 0..63
            #pragma unroll
            for (int i = 0; i < 4; ++i) {
                const int c = i*64 + cbase;
                const float4 vv = *reinterpret_cast<const float4*>(&vb[c*N_POS + m0 + kl4*4]);
                vs[kl4*4+0][c] = vv.x; vs[kl4*4+1][c] = vv.y;
                vs[kl4*4+2][c] = vv.z; vs[kl4*4+3][c] = vv.w;
            }
        }
        __syncthreads();

        // scores: thread (ql, kg) -> kl = kg*4+j
        float sv[4];
        #pragma unroll
        for (int j = 0; j < 4; ++j) {
            const int kl = kg*4 + j;
            float s = 0.f;
            #pragma unroll
            for (int o4 = 0; o4 < 8; ++o4) {
                const float4 k4 = *reinterpret_cast<const float4*>(&ks[kl][o4*4]);
                s += k4.x*qv[o4*4+0] + k4.y*qv[o4*4+1] + k4.z*qv[o4*4+2] + k4.w*qv[o4*4+3];
            }
            sv[j] = s;
        }
        pmaxs[kg][ql] = fmaxf(fmaxf(sv[0], sv[1]), fmaxf(sv[2], sv[3]));
        __syncthreads();

        if (tid < 64) {
            const int q = tid;
            const float mold = m_s[q];
            float mm = mold;
            #pragma unroll
            for (int g = 0; g < 8; ++g) mm = fmaxf(mm, pmaxs[g][q]);
            const float f = __expf(mold - mm);   // exp(-inf)=0 on first tile
            f_s[q] = f;
            l_s[q] *= f;
            m_s[q] = mm;
        }
        __syncthreads();

        {
            const float mm = m_s[ql];
            float lp = 0.f;
            #pragma unroll
            for (int j = 0; j < 4; ++j) {
                const float p = __expf(sv[j] - mm);
                ps[kg*4+j][ql] = p;
                lp += p;
            }
            psums[kg][ql] = lp;
        }
        __syncthreads();

        if (tid < 64) {
            float a = 0.f;
            #pragma unroll
            for (int g = 0; g < 8; ++g) a += psums[g][tid];
            l_s[tid] += a;
        }

        // PV: oacc[w][j] += p[k][qg*8+j] * v[k][c4+64w]
        {
            #pragma unroll
            for (int j = 0; j < 8; ++j) {
                const float fj = f_s[qg*8 + j];
                #pragma unroll
                for (int w = 0; w < 4; ++w) oacc[w][j] *= fj;
            }
            for (int k = 0; k < 32; ++k) {
                const float4 p0 = *reinterpret_cast<const float4*>(&ps[k][qg*8]);
                const float4 p1 = *reinterpret_cast<const float4*>(&ps[k][qg*8+4]);
                float vw[4];
                #pragma unroll
                for (int w = 0; w < 4; ++w) vw[w] = vs[k][c4 + w*64];
                #pragma unroll
                for (int w = 0; w < 4; ++w) {
                    oacc[w][0] += p0.x*vw[w]; oacc[w][1] += p0.y*vw[w];
                    oacc[w][2] += p0.z*vw[w]; oacc[w][3] += p0.w*vw[w];
                    oacc[w][4] += p1.x*vw[w]; oacc[w][5] += p1.y*vw[w];
                    oacc[w][6] += p1.z*vw[w]; oacc[w][7] += p1.w*vw[w];
                }
            }
        }
        __syncthreads();
    }

    // write o_ws[b][n][c], fold 1/l
    #pragma unroll
    for (int j = 0; j < 8; ++j) {
        const int q = qg*8 + j;
        const float invl = 1.0f / l_s[q];
        #pragma unroll
        for (int w = 0; w < 4; ++w)
            o_ws[((b*N_POS) + n0 + q)*C_DIM + c4 + w*64] = oacc[w][j] * invl;
    }
}

__global__ __launch_bounds__(256) void out_combine(
    const float* __restrict__ o_ws, const float* __restrict__ x,
    const float* __restrict__ gamma, float* __restrict__ out)
{
    __shared__ float t[64][65];
    const int tid = threadIdx.x;
    const int jj = tid & 63;
    const int ig = tid >> 6;
    const int nt = blockIdx.x;  // 0..63
    const int ct = blockIdx.y;  // 0..3
    const int b  = blockIdx.z;  // 0..3
    const int n0 = nt*64, c0 = ct*64;
    const float g = gamma[0];

    #pragma unroll
    for (int ii = 0; ii < 16; ++ii) {
        const int i = ii*4 + ig;   // n-local
        t[i][jj] = o_ws[((b*N_POS) + n0 + i)*C_DIM + c0 + jj];
    }
    __syncthreads();
    #pragma unroll
    for (int ii = 0; ii < 16; ++ii) {
        const int cl = ii*4 + ig;  // c-local
        const int idx = ((b*C_DIM) + c0 + cl)*N_POS + n0 + jj;
        out[idx] = g * t[jj][cl] + x[idx];
    }
}

extern "C" void kernel_launch(void* const* d_in, const int* in_sizes, int n_in,
                              void* d_out, int out_size, void* d_ws, size_t ws_size,
                              hipStream_t stream)
{
    const float* x     = (const float*)d_in[0];
    const float* Wq    = (const float*)d_in[1];
    const float* bq    = (const float*)d_in[2];
    const float* Wk    = (const float*)d_in[3];
    const float* bk    = (const float*)d_in[4];
    const float* Wv    = (const float*)d_in[5];
    const float* bv    = (const float*)d_in[6];
    const float* gamma = (const float*)d_in[7];

    float* ws   = (float*)d_ws;
    float* q_ws = ws;
    float* k_ws = ws + 4*CQK_D*N_POS;            // 524288
    float* v_ws = ws + 8*CQK_D*N_POS;            // 1048576
    float* o_ws = v_ws + 4*C_DIM*N_POS;          // 5242880
    float* out  = (float*)d_out;

    qkv_proj<<<dim3(64,5,4), 256, 0, stream>>>(x, Wq, bq, Wk, bk, Wv, bv, q_ws, k_ws, v_ws);
    flash_attn<<<dim3(64,4), 512, 0, stream>>>(q_ws, k_ws, v_ws, o_ws);
    out_combine<<<dim3(64,4,4), 256, 0, stream>>>(o_ws, x, gamma, out);
}

// Round 3
// 332.063 us; speedup vs baseline: 2.6591x; 2.6591x over previous
//
#include <hip/hip_runtime.h>
#include <math.h>
#include <stdint.h>

#define N_POS 4096
#define C_DIM 256
#define CQK_D 32

typedef __attribute__((ext_vector_type(8))) short bf16x8;
typedef __attribute__((ext_vector_type(4))) float f32x4;
typedef __attribute__((ext_vector_type(4))) uint32_t u32x4;

__device__ inline uint16_t f2bf(float f){
  uint32_t u = __float_as_uint(f);
  return (uint16_t)((u + 0x7FFFu + ((u>>16)&1u)) >> 16);
}
__device__ inline uint32_t pk2bf(float a, float b){
  return (uint32_t)f2bf(a) | ((uint32_t)f2bf(b)<<16);
}

// ---------------- QKV projection (fp32 math, bf16 outputs) ----------------
// q_bf,k_bf: [B][N][32] row-major; v_bf: [B][256][N]
__global__ __launch_bounds__(256) void qkv_proj(
    const float* __restrict__ x,
    const float* __restrict__ Wq, const float* __restrict__ bq,
    const float* __restrict__ Wk, const float* __restrict__ bk,
    const float* __restrict__ Wv, const float* __restrict__ bv,
    ushort* __restrict__ q_bf, ushort* __restrict__ k_bf, ushort* __restrict__ v_bf)
{
    __shared__ float xs[128][64];
    const int tid  = threadIdx.x;
    const int col  = tid & 63;
    const int rgrp = tid >> 6;
    const int nt = blockIdx.x;
    const int rt = blockIdx.y;
    const int b  = blockIdx.z;
    const int n0 = nt * 64;

    const float* W; const float* bias; int row;
    if (rt == 0) {
        if (rgrp < 2) { W = Wq; bias = bq; row = rgrp*16; }
        else          { W = Wk; bias = bk; row = (rgrp-2)*16; }
    } else {
        W = Wv; bias = bv; row = (rt-1)*64 + rgrp*16;
    }

    float acc[16];
    #pragma unroll
    for (int j = 0; j < 16; ++j) acc[j] = bias[row + j];

    for (int ch = 0; ch < 2; ++ch) {
        #pragma unroll
        for (int i = 0; i < 32; ++i) {
            const int cl = i*4 + rgrp;
            xs[cl][col] = x[((b*C_DIM) + ch*128 + cl)*N_POS + n0 + col];
        }
        __syncthreads();
        #pragma unroll 8
        for (int cc = 0; cc < 128; cc += 4) {
            const float xv0 = xs[cc+0][col], xv1 = xs[cc+1][col];
            const float xv2 = xs[cc+2][col], xv3 = xs[cc+3][col];
            #pragma unroll
            for (int j = 0; j < 16; ++j) {
                const float4 w = *reinterpret_cast<const float4*>(&W[(row+j)*C_DIM + ch*128 + cc]);
                acc[j] += w.x*xv0 + w.y*xv1 + w.z*xv2 + w.w*xv3;
            }
        }
        __syncthreads();
    }

    if (rt == 0) {
        ushort* outbf = (rgrp < 2 ? q_bf : k_bf) + (size_t)b*N_POS*CQK_D;
        uint32_t pk[8];
        #pragma unroll
        for (int jj = 0; jj < 8; ++jj) pk[jj] = pk2bf(acc[2*jj], acc[2*jj+1]);
        ushort* p = outbf + (size_t)(n0 + col)*CQK_D + row;
        uint4 u0; u0.x = pk[0]; u0.y = pk[1]; u0.z = pk[2]; u0.w = pk[3];
        uint4 u1; u1.x = pk[4]; u1.y = pk[5]; u1.z = pk[6]; u1.w = pk[7];
        *reinterpret_cast<uint4*>(p)     = u0;
        *reinterpret_cast<uint4*>(p + 8) = u1;
    } else {
        ushort* outbf = v_bf + (size_t)b*C_DIM*N_POS;
        #pragma unroll
        for (int j = 0; j < 16; ++j)
            outbf[(size_t)(row + j)*N_POS + n0 + col] = f2bf(acc[j]);
    }
}

// ---------------- Flash attention, bf16 MFMA, LDS-mediated P exchange ----------------
// Swapped QK^T: S^T = mfma(K_frag, Q_frag): D[key][q], q=lane&15, key=4*(lane>>4)+reg (+16t).
// PV: O^T = mfma(V_frag, P_frag): D[c][q].
// LDS layouts (XOR-swizzled, mask ((row&7)<<4) on byte addr within 128B row):
//   vt: [c=256][k-bytes 128]   (V chunk, bf16)
//   pt: per-wave [q=16][k-bytes 128] (P chunk, bf16)
__global__ __launch_bounds__(256) void flash_mfma(
    const ushort* __restrict__ q_bf, const ushort* __restrict__ k_bf,
    const ushort* __restrict__ v_bf, float* __restrict__ o_ws)
{
    __shared__ ushort vt[C_DIM*64];      // 32 KB
    __shared__ ushort pt[4*16*64];       // 8 KB

    const int tid  = threadIdx.x;
    const int wv   = tid >> 6;
    const int lane = tid & 63;
    const int g    = lane >> 4;          // 0..3
    const int q    = lane & 15;
    const int b    = blockIdx.y;
    const int n0   = blockIdx.x * 64;
    const int qrow = n0 + wv*16 + q;

    const ushort* qb = q_bf + (size_t)b*N_POS*CQK_D;
    const ushort* kb = k_bf + (size_t)b*N_POS*CQK_D;
    const ushort* vb = v_bf + (size_t)b*C_DIM*N_POS;

    const bf16x8 qfrag = *reinterpret_cast<const bf16x8*>(qb + (size_t)qrow*CQK_D + g*8);

    f32x4 zero4 = {0.f, 0.f, 0.f, 0.f};
    f32x4 acc[16];
    #pragma unroll
    for (int i = 0; i < 16; ++i) acc[i] = zero4;
    float m = -INFINITY, l = 0.f;

    // V staging: lane (hi=lane>>3, lo=lane&7); per s: row c = wv*64 + s*8 + hi,
    // global k-elems m0 + lo*8 .. +7; LDS dst byte = c*128 + ((lo ^ (c&7))<<4), c&7 = hi.
    const int st_hi = lane >> 3, st_lo = lane & 7;
    const ushort* vsrc0 = vb + (size_t)(wv*64 + st_hi)*N_POS + st_lo*8;
    char* vdst0 = (char*)vt + (wv*64 + st_hi)*128 + (((st_lo ^ st_hi) & 7) << 4);
    char* ptw   = (char*)pt + wv*2048;
    const int swq = (q & 7) << 4;

    for (int mt = 0; mt < 64; ++mt) {
        const int m0 = mt * 64;
        __syncthreads();                 // prev chunk's LDS reads complete

        // issue V global loads early (consumed after softmax)
        u32x4 vreg[8];
        #pragma unroll
        for (int s = 0; s < 8; ++s)
            vreg[s] = *reinterpret_cast<const u32x4*>(vsrc0 + (size_t)s*8*N_POS + m0);

        // QK^T (K frags direct from global, L2-hot)
        f32x4 sv[4];
        #pragma unroll
        for (int t = 0; t < 4; ++t) {
            const bf16x8 kf = *reinterpret_cast<const bf16x8*>(kb + (size_t)(m0 + t*16 + q)*CQK_D + g*8);
            sv[t] = __builtin_amdgcn_mfma_f32_16x16x32_bf16(kf, qfrag, zero4, 0, 0, 0);
        }

        // online softmax (unconditional rescale)
        float pmax = sv[0][0];
        #pragma unroll
        for (int t = 0; t < 4; ++t)
            #pragma unroll
            for (int r = 0; r < 4; ++r) pmax = fmaxf(pmax, sv[t][r]);
        pmax = fmaxf(pmax, __shfl_xor(pmax, 16));
        pmax = fmaxf(pmax, __shfl_xor(pmax, 32));
        const float mn = fmaxf(m, pmax);
        const float f = __expf(m - mn);  // 0 on first chunk
        l *= f;
        #pragma unroll
        for (int i = 0; i < 16; ++i) acc[i] *= f;
        m = mn;

        uint32_t pk[8];
        float psum = 0.f;
        #pragma unroll
        for (int t = 0; t < 4; ++t) {
            const float p0 = __expf(sv[t][0]-m), p1 = __expf(sv[t][1]-m);
            const float p2 = __expf(sv[t][2]-m), p3 = __expf(sv[t][3]-m);
            psum += (p0+p1)+(p2+p3);
            pk[2*t]   = pk2bf(p0, p1);
            pk[2*t+1] = pk2bf(p2, p3);
        }
        psum += __shfl_xor(psum, 16);
        psum += __shfl_xor(psum, 32);
        l += psum;

        // P writes: source lane (g,q) holds keys t*16+g*4+{0..3} for query q.
        // plain k-byte = t*32 + g*8 (+4 for the r=2,3 dword); swizzle ^= swq.
        #pragma unroll
        for (int t = 0; t < 4; ++t) {
            const int a = q*128 + ((t*32 + g*8) ^ swq);
            *reinterpret_cast<uint32_t*>(ptw + a)     = pk[2*t];
            *reinterpret_cast<uint32_t*>(ptw + a + 4) = pk[2*t+1];
        }
        // V writes (compiler inserts vmcnt wait for vreg)
        #pragma unroll
        for (int s = 0; s < 8; ++s)
            *reinterpret_cast<u32x4*>(vdst0 + s*1024) = vreg[s];

        __syncthreads();                 // LDS tiles visible to all

        // P B-frags: lane (g,q) needs keys mm*32 + g*8 + {0..7} of query q
        bf16x8 pb[2];
        #pragma unroll
        for (int mm = 0; mm < 2; ++mm)
            pb[mm] = *reinterpret_cast<const bf16x8*>(ptw + q*128 + ((mm*64 + g*16) ^ swq));

        // PV: A-frag = V[c = ct*16 + q][keys mm*32 + g*8 + {0..7}]
        #pragma unroll
        for (int mm = 0; mm < 2; ++mm) {
            #pragma unroll
            for (int ct = 0; ct < 16; ++ct) {
                const bf16x8 vf = *reinterpret_cast<const bf16x8*>(
                    (char*)vt + (ct*16 + q)*128 + ((mm*64 + g*16) ^ swq));
                acc[ct] = __builtin_amdgcn_mfma_f32_16x16x32_bf16(vf, pb[mm], acc[ct], 0, 0, 0);
            }
        }
    }

    const float invl = 1.f / l;
    float* orow = o_ws + ((size_t)b*N_POS + qrow)*C_DIM + g*4;
    #pragma unroll
    for (int ct = 0; ct < 16; ++ct) {
        f32x4 o = acc[ct] * invl;
        *reinterpret_cast<f32x4*>(orow + ct*16) = o;
    }
}

// ---------------- transpose + gamma*out + x ----------------
__global__ __launch_bounds__(256) void out_combine(
    const float* __restrict__ o_ws, const float* __restrict__ x,
    const float* __restrict__ gamma, float* __restrict__ out)
{
    __shared__ float t[64][65];
    const int tid = threadIdx.x;
    const int jj = tid & 63;
    const int ig = tid >> 6;
    const int nt = blockIdx.x;
    const int ct = blockIdx.y;
    const int b  = blockIdx.z;
    const int n0 = nt*64, c0 = ct*64;
    const float gm = gamma[0];

    #pragma unroll
    for (int ii = 0; ii < 16; ++ii) {
        const int i = ii*4 + ig;
        t[i][jj] = o_ws[((size_t)(b*N_POS) + n0 + i)*C_DIM + c0 + jj];
    }
    __syncthreads();
    #pragma unroll
    for (int ii = 0; ii < 16; ++ii) {
        const int cl = ii*4 + ig;
        const size_t idx = ((size_t)(b*C_DIM) + c0 + cl)*N_POS + n0 + jj;
        out[idx] = gm * t[jj][cl] + x[idx];
    }
}

extern "C" void kernel_launch(void* const* d_in, const int* in_sizes, int n_in,
                              void* d_out, int out_size, void* d_ws, size_t ws_size,
                              hipStream_t stream)
{
    const float* x     = (const float*)d_in[0];
    const float* Wq    = (const float*)d_in[1];
    const float* bq    = (const float*)d_in[2];
    const float* Wk    = (const float*)d_in[3];
    const float* bk    = (const float*)d_in[4];
    const float* Wv    = (const float*)d_in[5];
    const float* bv    = (const float*)d_in[6];
    const float* gamma = (const float*)d_in[7];

    // ws layout: o_ws f32 [4][4096][256] (16MB) | q_bf | k_bf (1MB each) | v_bf (8MB)
    float*  o_ws = (float*)d_ws;
    ushort* q_bf = (ushort*)((char*)d_ws + (16u<<20));
    ushort* k_bf = q_bf + (size_t)4*N_POS*CQK_D;
    ushort* v_bf = k_bf + (size_t)4*N_POS*CQK_D;
    float* out = (float*)d_out;

    qkv_proj<<<dim3(64,5,4), 256, 0, stream>>>(x, Wq, bq, Wk, bk, Wv, bv, q_bf, k_bf, v_bf);
    flash_mfma<<<dim3(64,4), 256, 0, stream>>>(q_bf, k_bf, v_bf, o_ws);
    out_combine<<<dim3(64,4,4), 256, 0, stream>>>(o_ws, x, gamma, out);
}

// Round 4
// 167.869 us; speedup vs baseline: 5.2599x; 1.9781x over previous
//
#include <hip/hip_runtime.h>
#include <math.h>
#include <stdint.h>

#define N_POS 4096
#define C_DIM 256
#define CQK_D 32

typedef __attribute__((ext_vector_type(8))) short bf16x8;
typedef __attribute__((ext_vector_type(4))) float f32x4;
typedef __attribute__((ext_vector_type(4))) uint32_t u32x4;

__device__ inline uint16_t f2bf(float f){
  uint32_t u = __float_as_uint(f);
  return (uint16_t)((u + 0x7FFFu + ((u>>16)&1u)) >> 16);
}
__device__ inline uint32_t pk2bf(float a, float b){
  return (uint32_t)f2bf(a) | ((uint32_t)f2bf(b)<<16);
}
__device__ inline float bf2f(ushort u){
  return __uint_as_float(((uint32_t)u) << 16);
}

// ---------------- prep: x transpose -> xT_bf [B][N][256], W concat -> W_bf[320][256], bias_f[320]
__global__ __launch_bounds__(256) void prep(
    const float* __restrict__ x,
    const float* __restrict__ Wq, const float* __restrict__ bq,
    const float* __restrict__ Wk, const float* __restrict__ bk,
    const float* __restrict__ Wv, const float* __restrict__ bv,
    ushort* __restrict__ xT_bf, ushort* __restrict__ W_bf, float* __restrict__ bias_f)
{
    const int tid = threadIdx.x;
    if (blockIdx.x == 64) {
        // W conversion: 16 sub-blocks cover 320*256 = 81920 elems
        const int sub = blockIdx.z * 4 + blockIdx.y;   // 0..15
        const int e0 = sub * 5120;
        for (int e = e0 + tid; e < e0 + 5120; e += 256) {
            const int o = e >> 8, c = e & 255;
            float w;
            if (o < 32)       w = Wq[o*C_DIM + c];
            else if (o < 64)  w = Wk[(o-32)*C_DIM + c];
            else              w = Wv[(o-64)*C_DIM + c];
            W_bf[e] = f2bf(w);
        }
        if (sub == 0) {
            for (int i = tid; i < 320; i += 256)
                bias_f[i] = (i < 32) ? bq[i] : (i < 64) ? bk[i-32] : bv[i-64];
        }
        return;
    }
    __shared__ float t[64][65];
    const int jj = tid & 63;
    const int ig = tid >> 6;
    const int n0 = blockIdx.x * 64;
    const int c0 = blockIdx.y * 64;
    const int b  = blockIdx.z;
    #pragma unroll
    for (int ii = 0; ii < 16; ++ii) {
        const int cl = ii*4 + ig;
        t[cl][jj] = x[((size_t)(b*C_DIM) + c0 + cl)*N_POS + n0 + jj];
    }
    __syncthreads();
    #pragma unroll
    for (int ii = 0; ii < 8; ++ii) {
        const int flat = ii*256 + tid;
        const int nl = flat >> 5;          // 0..63
        const int cp = flat & 31;          // c-pair
        const uint32_t d = pk2bf(t[2*cp][nl], t[2*cp+1][nl]);
        *reinterpret_cast<uint32_t*>(xT_bf + ((size_t)(b*N_POS) + n0 + nl)*C_DIM + c0 + 2*cp) = d;
    }
}

// ---------------- qkv projection as bf16 MFMA GEMM ----------------
// Out[o,n] = sum_c W_bf[o,c] * xT_bf[n,c];  D = mfma(W_frag, X_frag) -> D[o-row][n-col]
__global__ __launch_bounds__(256, 2) void qkv_gemm(
    const ushort* __restrict__ xT_bf, const ushort* __restrict__ W_bf,
    const float* __restrict__ bias_f,
    ushort* __restrict__ q_bf, ushort* __restrict__ k_bf, ushort* __restrict__ v_bf)
{
    __shared__ ushort xs[64*C_DIM];      // 32 KB, XOR-swizzled rows of 512B
    const int tid  = threadIdx.x;
    const int wv   = tid >> 6;
    const int lane = tid & 63;
    const int g    = lane >> 4;
    const int q    = lane & 15;
    const int b    = blockIdx.y;
    const int n0   = blockIdx.x * 64;

    // stage xT tile [64 n][256 c] bf16: linear LDS dest, inverse-swizzled global src
    {
        const char* xTb = (const char*)(xT_bf + ((size_t)(b*N_POS) + n0)*C_DIM);
        const int n_l    = (tid*16) >> 9;            // row this lane fills (s=0)
        const int inner  = (tid & 31) << 4;          // byte within row
        #pragma unroll
        for (int s = 0; s < 8; ++s) {
            const int n = s*8 + n_l;
            const int src_inner = inner ^ ((n & 7) << 4);
            __builtin_amdgcn_global_load_lds(
                (const __attribute__((address_space(1))) uint32_t*)(xTb + (size_t)n*512 + src_inner),
                (__attribute__((address_space(3))) uint32_t*)((char*)xs + s*4096 + wv*1024),
                16, 0, 0);
        }
    }
    __syncthreads();

    f32x4 zero4 = {0.f,0.f,0.f,0.f};
    f32x4 acc[20];
    #pragma unroll
    for (int i = 0; i < 20; ++i) acc[i] = zero4;

    const char* xrow = (const char*)xs + (wv*16 + q)*512;
    const int sw = (q & 7) << 4;

    #pragma unroll
    for (int kk = 0; kk < 8; ++kk) {
        const bf16x8 xf = *reinterpret_cast<const bf16x8*>(xrow + ((kk*64 + g*16) ^ sw));
        const ushort* wrow = W_bf + q*C_DIM + kk*32 + g*8;
        #pragma unroll
        for (int ot = 0; ot < 20; ++ot) {
            const bf16x8 wf = *reinterpret_cast<const bf16x8*>(wrow + ot*16*C_DIM);
            acc[ot] = __builtin_amdgcn_mfma_f32_16x16x32_bf16(wf, xf, acc[ot], 0, 0, 0);
        }
    }

    // epilogue: lane (g,q) reg r -> o = ot*16 + 4g + r, n = n0 + wv*16 + q
    const int n = n0 + wv*16 + q;
    // q, k outputs: [B][N][32]
    #pragma unroll
    for (int ot = 0; ot < 4; ++ot) {
        const int ob = ot*16 + 4*g;
        const float4 bi = *reinterpret_cast<const float4*>(bias_f + ob);
        const uint32_t u0 = pk2bf(acc[ot][0] + bi.x, acc[ot][1] + bi.y);
        const uint32_t u1 = pk2bf(acc[ot][2] + bi.z, acc[ot][3] + bi.w);
        ushort* dst = (ot < 2 ? q_bf : k_bf) + ((size_t)(b*N_POS) + n)*CQK_D + (ob & 31);
        uint2 u; u.x = u0; u.y = u1;
        *reinterpret_cast<uint2*>(dst) = u;
    }
    // v output: [B][256][N]
    ushort* vB = v_bf + (size_t)(b*C_DIM)*N_POS + n;
    #pragma unroll
    for (int ot = 4; ot < 20; ++ot) {
        const int ob = ot*16 + 4*g;
        const float4 bi = *reinterpret_cast<const float4*>(bias_f + ob);
        const int c = ob - 64;
        vB[(size_t)(c+0)*N_POS] = f2bf(acc[ot][0] + bi.x);
        vB[(size_t)(c+1)*N_POS] = f2bf(acc[ot][1] + bi.y);
        vB[(size_t)(c+2)*N_POS] = f2bf(acc[ot][2] + bi.z);
        vB[(size_t)(c+3)*N_POS] = f2bf(acc[ot][3] + bi.w);
    }
}

// ---------------- Flash attention, bf16 MFMA (unchanged core, bf16 output) ----------------
__global__ __launch_bounds__(256) void flash_mfma(
    const ushort* __restrict__ q_bf, const ushort* __restrict__ k_bf,
    const ushort* __restrict__ v_bf, ushort* __restrict__ o_bf)
{
    __shared__ ushort vt[C_DIM*64];      // 32 KB
    __shared__ ushort pt[4*16*64];       // 8 KB

    const int tid  = threadIdx.x;
    const int wv   = tid >> 6;
    const int lane = tid & 63;
    const int g    = lane >> 4;
    const int q    = lane & 15;
    const int b    = blockIdx.y;
    const int n0   = blockIdx.x * 64;
    const int qrow = n0 + wv*16 + q;

    const ushort* qb = q_bf + (size_t)b*N_POS*CQK_D;
    const ushort* kb = k_bf + (size_t)b*N_POS*CQK_D;
    const ushort* vb = v_bf + (size_t)b*C_DIM*N_POS;

    const bf16x8 qfrag = *reinterpret_cast<const bf16x8*>(qb + (size_t)qrow*CQK_D + g*8);

    f32x4 zero4 = {0.f, 0.f, 0.f, 0.f};
    f32x4 acc[16];
    #pragma unroll
    for (int i = 0; i < 16; ++i) acc[i] = zero4;
    float m = -INFINITY, l = 0.f;

    const int st_hi = lane >> 3, st_lo = lane & 7;
    const ushort* vsrc0 = vb + (size_t)(wv*64 + st_hi)*N_POS + st_lo*8;
    char* vdst0 = (char*)vt + (wv*64 + st_hi)*128 + (((st_lo ^ st_hi) & 7) << 4);
    char* ptw   = (char*)pt + wv*2048;
    const int swq = (q & 7) << 4;

    for (int mt = 0; mt < 64; ++mt) {
        const int m0 = mt * 64;
        __syncthreads();

        u32x4 vreg[8];
        #pragma unroll
        for (int s = 0; s < 8; ++s)
            vreg[s] = *reinterpret_cast<const u32x4*>(vsrc0 + (size_t)s*8*N_POS + m0);

        f32x4 sv[4];
        #pragma unroll
        for (int t = 0; t < 4; ++t) {
            const bf16x8 kf = *reinterpret_cast<const bf16x8*>(kb + (size_t)(m0 + t*16 + q)*CQK_D + g*8);
            sv[t] = __builtin_amdgcn_mfma_f32_16x16x32_bf16(kf, qfrag, zero4, 0, 0, 0);
        }

        float pmax = sv[0][0];
        #pragma unroll
        for (int t = 0; t < 4; ++t)
            #pragma unroll
            for (int r = 0; r < 4; ++r) pmax = fmaxf(pmax, sv[t][r]);
        pmax = fmaxf(pmax, __shfl_xor(pmax, 16));
        pmax = fmaxf(pmax, __shfl_xor(pmax, 32));
        const float mn = fmaxf(m, pmax);
        const float f = __expf(m - mn);
        l *= f;
        #pragma unroll
        for (int i = 0; i < 16; ++i) acc[i] *= f;
        m = mn;

        uint32_t pk[8];
        float psum = 0.f;
        #pragma unroll
        for (int t = 0; t < 4; ++t) {
            const float p0 = __expf(sv[t][0]-m), p1 = __expf(sv[t][1]-m);
            const float p2 = __expf(sv[t][2]-m), p3 = __expf(sv[t][3]-m);
            psum += (p0+p1)+(p2+p3);
            pk[2*t]   = pk2bf(p0, p1);
            pk[2*t+1] = pk2bf(p2, p3);
        }
        psum += __shfl_xor(psum, 16);
        psum += __shfl_xor(psum, 32);
        l += psum;

        #pragma unroll
        for (int t = 0; t < 4; ++t) {
            const int a = q*128 + ((t*32 + g*8) ^ swq);
            *reinterpret_cast<uint32_t*>(ptw + a)     = pk[2*t];
            *reinterpret_cast<uint32_t*>(ptw + a + 4) = pk[2*t+1];
        }
        #pragma unroll
        for (int s = 0; s < 8; ++s)
            *reinterpret_cast<u32x4*>(vdst0 + s*1024) = vreg[s];

        __syncthreads();

        bf16x8 pb[2];
        #pragma unroll
        for (int mm = 0; mm < 2; ++mm)
            pb[mm] = *reinterpret_cast<const bf16x8*>(ptw + q*128 + ((mm*64 + g*16) ^ swq));

        #pragma unroll
        for (int mm = 0; mm < 2; ++mm) {
            #pragma unroll
            for (int ct = 0; ct < 16; ++ct) {
                const bf16x8 vf = *reinterpret_cast<const bf16x8*>(
                    (char*)vt + (ct*16 + q)*128 + ((mm*64 + g*16) ^ swq));
                acc[ct] = __builtin_amdgcn_mfma_f32_16x16x32_bf16(vf, pb[mm], acc[ct], 0, 0, 0);
            }
        }
    }

    const float invl = 1.f / l;
    char* orow = (char*)o_bf + ((size_t)(b*N_POS) + qrow)*512 + g*8;
    #pragma unroll
    for (int ct = 0; ct < 16; ++ct) {
        const uint32_t u0 = pk2bf(acc[ct][0]*invl, acc[ct][1]*invl);
        const uint32_t u1 = pk2bf(acc[ct][2]*invl, acc[ct][3]*invl);
        uint2 u; u.x = u0; u.y = u1;
        *reinterpret_cast<uint2*>(orow + ct*32) = u;
    }
}

// ---------------- transpose + gamma*out + x ----------------
__global__ __launch_bounds__(256) void out_combine(
    const ushort* __restrict__ o_bf, const float* __restrict__ x,
    const float* __restrict__ gamma, float* __restrict__ out)
{
    __shared__ float t[64][65];
    const int tid = threadIdx.x;
    const int jj = tid & 63;
    const int ig = tid >> 6;
    const int nt = blockIdx.x;
    const int ct = blockIdx.y;
    const int b  = blockIdx.z;
    const int n0 = nt*64, c0 = ct*64;
    const float gm = gamma[0];

    #pragma unroll
    for (int ii = 0; ii < 8; ++ii) {
        const int flat = ii*256 + tid;
        const int nl = flat >> 5;
        const int cp = flat & 31;
        const uint32_t d = *reinterpret_cast<const uint32_t*>(
            o_bf + ((size_t)(b*N_POS) + n0 + nl)*C_DIM + c0 + 2*cp);
        t[nl][2*cp]   = __uint_as_float(d << 16);
        t[nl][2*cp+1] = __uint_as_float(d & 0xFFFF0000u);
    }
    __syncthreads();
    #pragma unroll
    for (int ii = 0; ii < 16; ++ii) {
        const int cl = ii*4 + ig;
        const size_t idx = ((size_t)(b*C_DIM) + c0 + cl)*N_POS + n0 + jj;
        out[idx] = gm * t[jj][cl] + x[idx];
    }
}

extern "C" void kernel_launch(void* const* d_in, const int* in_sizes, int n_in,
                              void* d_out, int out_size, void* d_ws, size_t ws_size,
                              hipStream_t stream)
{
    const float* x     = (const float*)d_in[0];
    const float* Wq    = (const float*)d_in[1];
    const float* bq    = (const float*)d_in[2];
    const float* Wk    = (const float*)d_in[3];
    const float* bk    = (const float*)d_in[4];
    const float* Wv    = (const float*)d_in[5];
    const float* bv    = (const float*)d_in[6];
    const float* gamma = (const float*)d_in[7];

    // ws: o_bf 8MB | q_bf 1MB | k_bf 1MB | v_bf 8MB | xT_bf 8MB | W_bf 160KB | bias 1.25KB
    ushort* o_bf  = (ushort*)d_ws;
    ushort* q_bf  = o_bf + (size_t)4*N_POS*C_DIM;
    ushort* k_bf  = q_bf + (size_t)4*N_POS*CQK_D;
    ushort* v_bf  = k_bf + (size_t)4*N_POS*CQK_D;
    ushort* xT_bf = v_bf + (size_t)4*C_DIM*N_POS;
    ushort* W_bf  = xT_bf + (size_t)4*N_POS*C_DIM;
    float*  bias_f = (float*)(W_bf + 320*C_DIM);
    float* out = (float*)d_out;

    prep<<<dim3(65,4,4), 256, 0, stream>>>(x, Wq, bq, Wk, bk, Wv, bv, xT_bf, W_bf, bias_f);
    qkv_gemm<<<dim3(64,4), 256, 0, stream>>>(xT_bf, W_bf, bias_f, q_bf, k_bf, v_bf);
    flash_mfma<<<dim3(64,4), 256, 0, stream>>>(q_bf, k_bf, v_bf, o_bf);
    out_combine<<<dim3(64,4,4), 256, 0, stream>>>(o_bf, x, gamma, out);
}

// Round 5
// 121.168 us; speedup vs baseline: 7.2872x; 1.3854x over previous
//
#include <hip/hip_runtime.h>
#include <math.h>
#include <stdint.h>

#define N_POS 4096
#define C_DIM 256
#define CQK_D 32

typedef __attribute__((ext_vector_type(8))) short bf16x8;
typedef __attribute__((ext_vector_type(4))) float f32x4;
typedef __attribute__((ext_vector_type(4))) uint32_t u32x4;

__device__ inline uint16_t f2bf(float f){
  uint32_t u = __float_as_uint(f);
  return (uint16_t)((u + 0x7FFFu + ((u>>16)&1u)) >> 16);
}
__device__ inline uint32_t pk2bf(float a, float b){
  return (uint32_t)f2bf(a) | ((uint32_t)f2bf(b)<<16);
}
__device__ inline float bf2f_lo(uint32_t d){ return __uint_as_float(d << 16); }
__device__ inline float bf2f_hi(uint32_t d){ return __uint_as_float(d & 0xFFFF0000u); }

// ---------------- prep: x transpose -> xT_bf [B][N][256], W concat -> W_bf[320][256], bias_f[320]
__global__ __launch_bounds__(256) void prep(
    const float* __restrict__ x,
    const float* __restrict__ Wq, const float* __restrict__ bq,
    const float* __restrict__ Wk, const float* __restrict__ bk,
    const float* __restrict__ Wv, const float* __restrict__ bv,
    ushort* __restrict__ xT_bf, ushort* __restrict__ W_bf, float* __restrict__ bias_f)
{
    const int tid = threadIdx.x;
    if (blockIdx.x == 64) {
        const int sub = blockIdx.z * 4 + blockIdx.y;   // 0..15
        const int e0 = sub * 5120;
        for (int e = e0 + tid; e < e0 + 5120; e += 256) {
            const int o = e >> 8, c = e & 255;
            float w;
            if (o < 32)       w = Wq[o*C_DIM + c];
            else if (o < 64)  w = Wk[(o-32)*C_DIM + c];
            else              w = Wv[(o-64)*C_DIM + c];
            W_bf[e] = f2bf(w);
        }
        if (sub == 0) {
            for (int i = tid; i < 320; i += 256)
                bias_f[i] = (i < 32) ? bq[i] : (i < 64) ? bk[i-32] : bv[i-64];
        }
        return;
    }
    __shared__ float t[64][65];
    const int jj = tid & 63;
    const int ig = tid >> 6;
    const int n0 = blockIdx.x * 64;
    const int c0 = blockIdx.y * 64;
    const int b  = blockIdx.z;
    #pragma unroll
    for (int ii = 0; ii < 16; ++ii) {
        const int cl = ii*4 + ig;
        t[cl][jj] = x[((size_t)(b*C_DIM) + c0 + cl)*N_POS + n0 + jj];
    }
    __syncthreads();
    #pragma unroll
    for (int ii = 0; ii < 8; ++ii) {
        const int flat = ii*256 + tid;
        const int nl = flat >> 5;
        const int cp = flat & 31;
        const uint32_t d = pk2bf(t[2*cp][nl], t[2*cp+1][nl]);
        *reinterpret_cast<uint32_t*>(xT_bf + ((size_t)(b*N_POS) + n0 + nl)*C_DIM + c0 + 2*cp) = d;
    }
}

// ---------------- qkv projection as bf16 MFMA GEMM ----------------
__global__ __launch_bounds__(256, 2) void qkv_gemm(
    const ushort* __restrict__ xT_bf, const ushort* __restrict__ W_bf,
    const float* __restrict__ bias_f,
    ushort* __restrict__ q_bf, ushort* __restrict__ k_bf, ushort* __restrict__ v_bf)
{
    __shared__ ushort xs[64*C_DIM];      // 32 KB, XOR-swizzled rows of 512B
    const int tid  = threadIdx.x;
    const int wv   = tid >> 6;
    const int lane = tid & 63;
    const int g    = lane >> 4;
    const int q    = lane & 15;
    const int b    = blockIdx.y;
    const int n0   = blockIdx.x * 64;

    {
        const char* xTb = (const char*)(xT_bf + ((size_t)(b*N_POS) + n0)*C_DIM);
        const int n_l    = (tid*16) >> 9;
        const int inner  = (tid & 31) << 4;
        #pragma unroll
        for (int s = 0; s < 8; ++s) {
            const int n = s*8 + n_l;
            const int src_inner = inner ^ ((n & 7) << 4);
            __builtin_amdgcn_global_load_lds(
                (const __attribute__((address_space(1))) uint32_t*)(xTb + (size_t)n*512 + src_inner),
                (__attribute__((address_space(3))) uint32_t*)((char*)xs + s*4096 + wv*1024),
                16, 0, 0);
        }
    }
    __syncthreads();

    f32x4 zero4 = {0.f,0.f,0.f,0.f};
    f32x4 acc[20];
    #pragma unroll
    for (int i = 0; i < 20; ++i) acc[i] = zero4;

    const char* xrow = (const char*)xs + (wv*16 + q)*512;
    const int sw = (q & 7) << 4;

    #pragma unroll
    for (int kk = 0; kk < 8; ++kk) {
        const bf16x8 xf = *reinterpret_cast<const bf16x8*>(xrow + ((kk*64 + g*16) ^ sw));
        const ushort* wrow = W_bf + q*C_DIM + kk*32 + g*8;
        #pragma unroll
        for (int ot = 0; ot < 20; ++ot) {
            const bf16x8 wf = *reinterpret_cast<const bf16x8*>(wrow + ot*16*C_DIM);
            acc[ot] = __builtin_amdgcn_mfma_f32_16x16x32_bf16(wf, xf, acc[ot], 0, 0, 0);
        }
    }

    const int n = n0 + wv*16 + q;
    #pragma unroll
    for (int ot = 0; ot < 4; ++ot) {
        const int ob = ot*16 + 4*g;
        const float4 bi = *reinterpret_cast<const float4*>(bias_f + ob);
        const uint32_t u0 = pk2bf(acc[ot][0] + bi.x, acc[ot][1] + bi.y);
        const uint32_t u1 = pk2bf(acc[ot][2] + bi.z, acc[ot][3] + bi.w);
        ushort* dst = (ot < 2 ? q_bf : k_bf) + ((size_t)(b*N_POS) + n)*CQK_D + (ob & 31);
        uint2 u; u.x = u0; u.y = u1;
        *reinterpret_cast<uint2*>(dst) = u;
    }
    ushort* vB = v_bf + (size_t)(b*C_DIM)*N_POS + n;
    #pragma unroll
    for (int ot = 4; ot < 20; ++ot) {
        const int ob = ot*16 + 4*g;
        const float4 bi = *reinterpret_cast<const float4*>(bias_f + ob);
        const int c = ob - 64;
        vB[(size_t)(c+0)*N_POS] = f2bf(acc[ot][0] + bi.x);
        vB[(size_t)(c+1)*N_POS] = f2bf(acc[ot][1] + bi.y);
        vB[(size_t)(c+2)*N_POS] = f2bf(acc[ot][2] + bi.z);
        vB[(size_t)(c+3)*N_POS] = f2bf(acc[ot][3] + bi.w);
    }
}

// ---------------- Flash attention, split-KV x2, bf16 MFMA ----------------
// o_part[half][b][n][256] (normalized per-half), ml[half][b][n] = (m, l)
__global__ __launch_bounds__(256) void flash_mfma(
    const ushort* __restrict__ q_bf, const ushort* __restrict__ k_bf,
    const ushort* __restrict__ v_bf, ushort* __restrict__ o_part,
    float2* __restrict__ ml)
{
    __shared__ ushort vt[C_DIM*64];      // 32 KB
    __shared__ ushort pt[4*16*64];       // 8 KB

    const int tid  = threadIdx.x;
    const int wv   = tid >> 6;
    const int lane = tid & 63;
    const int g    = lane >> 4;
    const int q    = lane & 15;
    const int half = blockIdx.y;
    const int b    = blockIdx.z;
    const int n0   = blockIdx.x * 64;
    const int qrow = n0 + wv*16 + q;
    const int mt0  = half * 32, mt1 = mt0 + 32;

    const ushort* qb = q_bf + (size_t)b*N_POS*CQK_D;
    const ushort* kb = k_bf + (size_t)b*N_POS*CQK_D;
    const ushort* vb = v_bf + (size_t)b*C_DIM*N_POS;

    const bf16x8 qfrag = *reinterpret_cast<const bf16x8*>(qb + (size_t)qrow*CQK_D + g*8);

    f32x4 zero4 = {0.f, 0.f, 0.f, 0.f};
    f32x4 acc[16];
    #pragma unroll
    for (int i = 0; i < 16; ++i) acc[i] = zero4;
    float m = -INFINITY, l = 0.f;

    const int st_hi = lane >> 3, st_lo = lane & 7;
    const ushort* vsrc0 = vb + (size_t)(wv*64 + st_hi)*N_POS + st_lo*8;
    char* vdst0 = (char*)vt + (wv*64 + st_hi)*128 + (((st_lo ^ st_hi) & 7) << 4);
    char* ptw   = (char*)pt + wv*2048;
    const int swq = (q & 7) << 4;

    auto loadK = [&](int mtx, bf16x8* kf) {
        const int mm = mtx * 64;
        #pragma unroll
        for (int t = 0; t < 4; ++t)
            kf[t] = *reinterpret_cast<const bf16x8*>(kb + (size_t)(mm + t*16 + q)*CQK_D + g*8);
    };

    auto chunk = [&](int mtx, bf16x8* kfc, bf16x8* kfn, int pfmt) {
        const int m0 = mtx * 64;
        __syncthreads();                 // prev chunk's LDS reads complete

        u32x4 vreg[8];
        #pragma unroll
        for (int s = 0; s < 8; ++s)
            vreg[s] = *reinterpret_cast<const u32x4*>(vsrc0 + (size_t)s*8*N_POS + m0);

        f32x4 sv[4];
        #pragma unroll
        for (int t = 0; t < 4; ++t)
            sv[t] = __builtin_amdgcn_mfma_f32_16x16x32_bf16(kfc[t], qfrag, zero4, 0, 0, 0);

        float pmax = sv[0][0];
        #pragma unroll
        for (int t = 0; t < 4; ++t)
            #pragma unroll
            for (int r = 0; r < 4; ++r) pmax = fmaxf(pmax, sv[t][r]);
        pmax = fmaxf(pmax, __shfl_xor(pmax, 16));
        pmax = fmaxf(pmax, __shfl_xor(pmax, 32));
        if (__any(pmax > m + 8.f)) {     // defer-max (T13)
            const float mn = fmaxf(m, pmax);
            const float f = __expf(m - mn);
            l *= f;
            #pragma unroll
            for (int i = 0; i < 16; ++i) acc[i] *= f;
            m = mn;
        }

        uint32_t pk[8];
        float psum = 0.f;
        #pragma unroll
        for (int t = 0; t < 4; ++t) {
            const float p0 = __expf(sv[t][0]-m), p1 = __expf(sv[t][1]-m);
            const float p2 = __expf(sv[t][2]-m), p3 = __expf(sv[t][3]-m);
            psum += (p0+p1)+(p2+p3);
            pk[2*t]   = pk2bf(p0, p1);
            pk[2*t+1] = pk2bf(p2, p3);
        }
        psum += __shfl_xor(psum, 16);
        psum += __shfl_xor(psum, 32);
        l += psum;

        loadK(pfmt, kfn);                // prefetch next chunk's K (stays in flight)

        #pragma unroll
        for (int t = 0; t < 4; ++t) {
            const int a = q*128 + ((t*32 + g*8) ^ swq);
            *reinterpret_cast<uint32_t*>(ptw + a)     = pk[2*t];
            *reinterpret_cast<uint32_t*>(ptw + a + 4) = pk[2*t+1];
        }
        #pragma unroll
        for (int s = 0; s < 8; ++s)
            *reinterpret_cast<u32x4*>(vdst0 + s*1024) = vreg[s];

        __syncthreads();

        bf16x8 pb[2];
        #pragma unroll
        for (int mm = 0; mm < 2; ++mm)
            pb[mm] = *reinterpret_cast<const bf16x8*>(ptw + q*128 + ((mm*64 + g*16) ^ swq));

        #pragma unroll
        for (int mm = 0; mm < 2; ++mm) {
            #pragma unroll
            for (int ct = 0; ct < 16; ++ct) {
                const bf16x8 vf = *reinterpret_cast<const bf16x8*>(
                    (char*)vt + (ct*16 + q)*128 + ((mm*64 + g*16) ^ swq));
                acc[ct] = __builtin_amdgcn_mfma_f32_16x16x32_bf16(vf, pb[mm], acc[ct], 0, 0, 0);
            }
        }
    };

    bf16x8 kfA[4], kfB[4];
    loadK(mt0, kfA);
    for (int mt = mt0; mt < mt1; mt += 2) {
        chunk(mt,   kfA, kfB, mt + 1);
        chunk(mt+1, kfB, kfA, (mt + 2 < mt1) ? mt + 2 : mt1 - 1);
    }

    const float invl = 1.f / l;
    char* orow = (char*)o_part + ((size_t)((half*4 + b)*N_POS) + qrow)*512 + g*8;
    #pragma unroll
    for (int ct = 0; ct < 16; ++ct) {
        const uint32_t u0 = pk2bf(acc[ct][0]*invl, acc[ct][1]*invl);
        const uint32_t u1 = pk2bf(acc[ct][2]*invl, acc[ct][3]*invl);
        uint2 u; u.x = u0; u.y = u1;
        *reinterpret_cast<uint2*>(orow + ct*32) = u;
    }
    if (g == 0) {
        float2 v; v.x = m; v.y = l;
        ml[(size_t)((half*4 + b)*N_POS) + qrow] = v;
    }
}

// ---------------- merge halves + transpose + gamma*out + x ----------------
__global__ __launch_bounds__(256) void out_combine(
    const ushort* __restrict__ o_part, const float2* __restrict__ ml,
    const float* __restrict__ x, const float* __restrict__ gamma,
    float* __restrict__ out)
{
    __shared__ float t[64][65];
    __shared__ float w1s[64], w2s[64];
    const int tid = threadIdx.x;
    const int jj = tid & 63;
    const int ig = tid >> 6;
    const int nt = blockIdx.x;
    const int ct = blockIdx.y;
    const int b  = blockIdx.z;
    const int n0 = nt*64, c0 = ct*64;
    const float gm = gamma[0];

    if (tid < 64) {
        const float2 a = ml[(size_t)((0*4 + b)*N_POS) + n0 + tid];
        const float2 c2 = ml[(size_t)((1*4 + b)*N_POS) + n0 + tid];
        const float mm = fmaxf(a.x, c2.x);
        const float e1 = __expf(a.x - mm) * a.y;
        const float e2 = __expf(c2.x - mm) * c2.y;
        const float inv = 1.f / (e1 + e2);
        w1s[tid] = e1 * inv;
        w2s[tid] = e2 * inv;
    }
    __syncthreads();

    #pragma unroll
    for (int ii = 0; ii < 8; ++ii) {
        const int flat = ii*256 + tid;
        const int nl = flat >> 5;
        const int cp = flat & 31;
        const uint32_t d1 = *reinterpret_cast<const uint32_t*>(
            o_part + ((size_t)((0*4 + b)*N_POS) + n0 + nl)*C_DIM + c0 + 2*cp);
        const uint32_t d2 = *reinterpret_cast<const uint32_t*>(
            o_part + ((size_t)((1*4 + b)*N_POS) + n0 + nl)*C_DIM + c0 + 2*cp);
        const float w1 = w1s[nl], w2 = w2s[nl];
        t[nl][2*cp]   = w1*bf2f_lo(d1) + w2*bf2f_lo(d2);
        t[nl][2*cp+1] = w1*bf2f_hi(d1) + w2*bf2f_hi(d2);
    }
    __syncthreads();
    #pragma unroll
    for (int ii = 0; ii < 16; ++ii) {
        const int cl = ii*4 + ig;
        const size_t idx = ((size_t)(b*C_DIM) + c0 + cl)*N_POS + n0 + jj;
        out[idx] = gm * t[jj][cl] + x[idx];
    }
}

extern "C" void kernel_launch(void* const* d_in, const int* in_sizes, int n_in,
                              void* d_out, int out_size, void* d_ws, size_t ws_size,
                              hipStream_t stream)
{
    const float* x     = (const float*)d_in[0];
    const float* Wq    = (const float*)d_in[1];
    const float* bq    = (const float*)d_in[2];
    const float* Wk    = (const float*)d_in[3];
    const float* bk    = (const float*)d_in[4];
    const float* Wv    = (const float*)d_in[5];
    const float* bv    = (const float*)d_in[6];
    const float* gamma = (const float*)d_in[7];

    // ws: o_part 16MB | ml 256KB | q_bf 1MB | k_bf 1MB | v_bf 8MB | xT_bf 8MB | W_bf 160KB | bias
    ushort* o_part = (ushort*)d_ws;
    float2* ml     = (float2*)(o_part + (size_t)2*4*N_POS*C_DIM);
    ushort* q_bf   = (ushort*)(ml + (size_t)2*4*N_POS);
    ushort* k_bf   = q_bf + (size_t)4*N_POS*CQK_D;
    ushort* v_bf   = k_bf + (size_t)4*N_POS*CQK_D;
    ushort* xT_bf  = v_bf + (size_t)4*C_DIM*N_POS;
    ushort* W_bf   = xT_bf + (size_t)4*N_POS*C_DIM;
    float*  bias_f = (float*)(W_bf + 320*C_DIM);
    float* out = (float*)d_out;

    prep<<<dim3(65,4,4), 256, 0, stream>>>(x, Wq, bq, Wk, bk, Wv, bv, xT_bf, W_bf, bias_f);
    qkv_gemm<<<dim3(64,4), 256, 0, stream>>>(xT_bf, W_bf, bias_f, q_bf, k_bf, v_bf);
    flash_mfma<<<dim3(64,2,4), 256, 0, stream>>>(q_bf, k_bf, v_bf, o_part, ml);
    out_combine<<<dim3(64,4,4), 256, 0, stream>>>(o_part, ml, x, gamma, out);
}

// Round 6
// 115.230 us; speedup vs baseline: 7.6628x; 1.0515x over previous
//
#include <hip/hip_runtime.h>
#include <math.h>
#include <stdint.h>

#define N_POS 4096
#define C_DIM 256
#define CQK_D 32
#define NSPLIT 3

typedef __attribute__((ext_vector_type(8))) short bf16x8;
typedef __attribute__((ext_vector_type(4))) float f32x4;
typedef __attribute__((ext_vector_type(4))) uint32_t u32x4;

__device__ inline uint16_t f2bf(float f){
  uint32_t u = __float_as_uint(f);
  return (uint16_t)((u + 0x7FFFu + ((u>>16)&1u)) >> 16);
}
__device__ inline uint32_t pk2bf(float a, float b){
  return (uint32_t)f2bf(a) | ((uint32_t)f2bf(b)<<16);
}
__device__ inline float bf2f_lo(uint32_t d){ return __uint_as_float(d << 16); }
__device__ inline float bf2f_hi(uint32_t d){ return __uint_as_float(d & 0xFFFF0000u); }

// ---------------- prep: x transpose -> xT_bf [B][N][256], W concat -> W_bf[320][256], bias_f[320]
__global__ __launch_bounds__(256) void prep(
    const float* __restrict__ x,
    const float* __restrict__ Wq, const float* __restrict__ bq,
    const float* __restrict__ Wk, const float* __restrict__ bk,
    const float* __restrict__ Wv, const float* __restrict__ bv,
    ushort* __restrict__ xT_bf, ushort* __restrict__ W_bf, float* __restrict__ bias_f)
{
    const int tid = threadIdx.x;
    if (blockIdx.x == 64) {
        const int sub = blockIdx.z * 4 + blockIdx.y;   // 0..15
        const int e0 = sub * 5120;
        for (int e = e0 + tid; e < e0 + 5120; e += 256) {
            const int o = e >> 8, c = e & 255;
            float w;
            if (o < 32)       w = Wq[o*C_DIM + c];
            else if (o < 64)  w = Wk[(o-32)*C_DIM + c];
            else              w = Wv[(o-64)*C_DIM + c];
            W_bf[e] = f2bf(w);
        }
        if (sub == 0) {
            for (int i = tid; i < 320; i += 256)
                bias_f[i] = (i < 32) ? bq[i] : (i < 64) ? bk[i-32] : bv[i-64];
        }
        return;
    }
    __shared__ float t[64][65];
    const int jj = tid & 63;
    const int ig = tid >> 6;
    const int n0 = blockIdx.x * 64;
    const int c0 = blockIdx.y * 64;
    const int b  = blockIdx.z;
    #pragma unroll
    for (int ii = 0; ii < 16; ++ii) {
        const int cl = ii*4 + ig;
        t[cl][jj] = x[((size_t)(b*C_DIM) + c0 + cl)*N_POS + n0 + jj];
    }
    __syncthreads();
    #pragma unroll
    for (int ii = 0; ii < 8; ++ii) {
        const int flat = ii*256 + tid;
        const int nl = flat >> 5;
        const int cp = flat & 31;
        const uint32_t d = pk2bf(t[2*cp][nl], t[2*cp+1][nl]);
        *reinterpret_cast<uint32_t*>(xT_bf + ((size_t)(b*N_POS) + n0 + nl)*C_DIM + c0 + 2*cp) = d;
    }
}

// ---------------- qkv projection as bf16 MFMA GEMM ----------------
__global__ __launch_bounds__(256, 2) void qkv_gemm(
    const ushort* __restrict__ xT_bf, const ushort* __restrict__ W_bf,
    const float* __restrict__ bias_f,
    ushort* __restrict__ q_bf, ushort* __restrict__ k_bf, ushort* __restrict__ v_bf)
{
    __shared__ ushort xs[64*C_DIM];      // 32 KB, XOR-swizzled rows of 512B
    const int tid  = threadIdx.x;
    const int wv   = tid >> 6;
    const int lane = tid & 63;
    const int g    = lane >> 4;
    const int q    = lane & 15;
    const int b    = blockIdx.y;
    const int n0   = blockIdx.x * 64;

    {
        const char* xTb = (const char*)(xT_bf + ((size_t)(b*N_POS) + n0)*C_DIM);
        const int n_l    = (tid*16) >> 9;
        const int inner  = (tid & 31) << 4;
        #pragma unroll
        for (int s = 0; s < 8; ++s) {
            const int n = s*8 + n_l;
            const int src_inner = inner ^ ((n & 7) << 4);
            __builtin_amdgcn_global_load_lds(
                (const __attribute__((address_space(1))) uint32_t*)(xTb + (size_t)n*512 + src_inner),
                (__attribute__((address_space(3))) uint32_t*)((char*)xs + s*4096 + wv*1024),
                16, 0, 0);
        }
    }
    __syncthreads();

    f32x4 zero4 = {0.f,0.f,0.f,0.f};
    f32x4 acc[20];
    #pragma unroll
    for (int i = 0; i < 20; ++i) acc[i] = zero4;

    const char* xrow = (const char*)xs + (wv*16 + q)*512;
    const int sw = (q & 7) << 4;

    #pragma unroll
    for (int kk = 0; kk < 8; ++kk) {
        const bf16x8 xf = *reinterpret_cast<const bf16x8*>(xrow + ((kk*64 + g*16) ^ sw));
        const ushort* wrow = W_bf + q*C_DIM + kk*32 + g*8;
        #pragma unroll
        for (int ot = 0; ot < 20; ++ot) {
            const bf16x8 wf = *reinterpret_cast<const bf16x8*>(wrow + ot*16*C_DIM);
            acc[ot] = __builtin_amdgcn_mfma_f32_16x16x32_bf16(wf, xf, acc[ot], 0, 0, 0);
        }
    }

    const int n = n0 + wv*16 + q;
    #pragma unroll
    for (int ot = 0; ot < 4; ++ot) {
        const int ob = ot*16 + 4*g;
        const float4 bi = *reinterpret_cast<const float4*>(bias_f + ob);
        const uint32_t u0 = pk2bf(acc[ot][0] + bi.x, acc[ot][1] + bi.y);
        const uint32_t u1 = pk2bf(acc[ot][2] + bi.z, acc[ot][3] + bi.w);
        ushort* dst = (ot < 2 ? q_bf : k_bf) + ((size_t)(b*N_POS) + n)*CQK_D + (ob & 31);
        uint2 u; u.x = u0; u.y = u1;
        *reinterpret_cast<uint2*>(dst) = u;
    }
    ushort* vB = v_bf + (size_t)(b*C_DIM)*N_POS + n;
    #pragma unroll
    for (int ot = 4; ot < 20; ++ot) {
        const int ob = ot*16 + 4*g;
        const float4 bi = *reinterpret_cast<const float4*>(bias_f + ob);
        const int c = ob - 64;
        vB[(size_t)(c+0)*N_POS] = f2bf(acc[ot][0] + bi.x);
        vB[(size_t)(c+1)*N_POS] = f2bf(acc[ot][1] + bi.y);
        vB[(size_t)(c+2)*N_POS] = f2bf(acc[ot][2] + bi.z);
        vB[(size_t)(c+3)*N_POS] = f2bf(acc[ot][3] + bi.w);
    }
}

// ---------------- Flash attention, split-KV x3, channel-split PV ----------------
// Wave wv: computes QK^T + softmax for its 16 queries (q-block wv), and
// PV for its 64-channel block (c-block wv) over ALL 64 queries.
// o_part[split][b][n][256] (normalized per-split, bf16), ml[split][b][n] = (m,l)
__global__ __launch_bounds__(256, 3) void flash_mfma(
    const ushort* __restrict__ q_bf, const ushort* __restrict__ k_bf,
    const ushort* __restrict__ v_bf, ushort* __restrict__ o_part,
    float2* __restrict__ ml)
{
    __shared__ ushort vt[C_DIM*64];      // 32 KB  [c][64k] swizzled
    __shared__ ushort pt[4*16*64];       // 8 KB   [qblock][16q][64k] swizzled
    __shared__ float  f_s[64];           // per-chunk rescale factors (reused for l at end)

    const int tid  = threadIdx.x;
    const int wv   = tid >> 6;
    const int lane = tid & 63;
    const int g    = lane >> 4;
    const int q    = lane & 15;
    const int half = blockIdx.y;         // 0..2
    const int b    = blockIdx.z;
    const int n0   = blockIdx.x * 64;
    const int qrow = n0 + wv*16 + q;
    const int mt0  = (half == 0) ? 0 : 22 + (half-1)*21;
    const int mt1  = mt0 + ((half == 0) ? 22 : 21);

    const ushort* qb = q_bf + (size_t)b*N_POS*CQK_D;
    const ushort* kb = k_bf + (size_t)b*N_POS*CQK_D;
    const ushort* vb = v_bf + (size_t)b*C_DIM*N_POS;

    const bf16x8 qfrag = *reinterpret_cast<const bf16x8*>(qb + (size_t)qrow*CQK_D + g*8);

    f32x4 zero4 = {0.f, 0.f, 0.f, 0.f};
    f32x4 acc[4][4];                     // [ct][qt]
    #pragma unroll
    for (int i = 0; i < 4; ++i)
        #pragma unroll
        for (int j = 0; j < 4; ++j) acc[i][j] = zero4;
    float m = -INFINITY, l = 0.f;

    const int st_hi = lane >> 3, st_lo = lane & 7;
    const ushort* vsrc0 = vb + (size_t)(wv*64 + st_hi)*N_POS + st_lo*8;
    char* vdst0 = (char*)vt + (wv*64 + st_hi)*128 + (((st_lo ^ st_hi) & 7) << 4);
    char* ptw   = (char*)pt + wv*2048;
    const int swq = (q & 7) << 4;

    auto loadK = [&](int mtx, bf16x8* kf) {
        const int mm = mtx * 64;
        #pragma unroll
        for (int t = 0; t < 4; ++t)
            kf[t] = *reinterpret_cast<const bf16x8*>(kb + (size_t)(mm + t*16 + q)*CQK_D + g*8);
    };

    auto chunk = [&](int mtx, bf16x8* kfc, bf16x8* kfn, int pfmt) {
        const int m0 = mtx * 64;
        __syncthreads();                 // prev chunk's LDS reads complete

        u32x4 vreg[8];                   // issue V loads early (T14)
        #pragma unroll
        for (int s = 0; s < 8; ++s)
            vreg[s] = *reinterpret_cast<const u32x4*>(vsrc0 + (size_t)s*8*N_POS + m0);

        f32x4 sv[4];
        #pragma unroll
        for (int t = 0; t < 4; ++t)
            sv[t] = __builtin_amdgcn_mfma_f32_16x16x32_bf16(kfc[t], qfrag, zero4, 0, 0, 0);

        float pmax = sv[0][0];
        #pragma unroll
        for (int t = 0; t < 4; ++t)
            #pragma unroll
            for (int r = 0; r < 4; ++r) pmax = fmaxf(pmax, sv[t][r]);
        pmax = fmaxf(pmax, __shfl_xor(pmax, 16));
        pmax = fmaxf(pmax, __shfl_xor(pmax, 32));
        float f = 1.f;
        if (__any(pmax > m + 8.f)) {     // defer-max (T13)
            const float mn = fmaxf(m, pmax);
            f = __expf(m - mn);          // 0 on first chunk
            l *= f;
            m = mn;
        }
        if (g == 0) f_s[wv*16 + q] = f;

        uint32_t pk[8];
        float psum = 0.f;
        #pragma unroll
        for (int t = 0; t < 4; ++t) {
            const float p0 = __expf(sv[t][0]-m), p1 = __expf(sv[t][1]-m);
            const float p2 = __expf(sv[t][2]-m), p3 = __expf(sv[t][3]-m);
            psum += (p0+p1)+(p2+p3);
            pk[2*t]   = pk2bf(p0, p1);
            pk[2*t+1] = pk2bf(p2, p3);
        }
        psum += __shfl_xor(psum, 16);
        psum += __shfl_xor(psum, 32);
        l += psum;

        loadK(pfmt, kfn);                // prefetch next chunk's K

        #pragma unroll
        for (int t = 0; t < 4; ++t) {
            const int a = q*128 + ((t*32 + g*8) ^ swq);
            *reinterpret_cast<uint32_t*>(ptw + a)     = pk[2*t];
            *reinterpret_cast<uint32_t*>(ptw + a + 4) = pk[2*t+1];
        }
        #pragma unroll
        for (int s = 0; s < 8; ++s)
            *reinterpret_cast<u32x4*>(vdst0 + s*1024) = vreg[s];

        __syncthreads();                 // pt, f_s, vt visible

        // rescale acc by f of each query column (skipped when all f==1)
        float f4[4];
        #pragma unroll
        for (int qt = 0; qt < 4; ++qt) f4[qt] = f_s[qt*16 + q];
        const bool anyr = (f4[0]!=1.f) | (f4[1]!=1.f) | (f4[2]!=1.f) | (f4[3]!=1.f);
        if (__any(anyr)) {
            #pragma unroll
            for (int ct = 0; ct < 4; ++ct)
                #pragma unroll
                for (int qt = 0; qt < 4; ++qt) acc[ct][qt] *= f4[qt];
        }

        // PV: wave's 64-channel block x all 64 queries
        #pragma unroll
        for (int mm = 0; mm < 2; ++mm) {
            bf16x8 vf[4];
            #pragma unroll
            for (int ct = 0; ct < 4; ++ct)
                vf[ct] = *reinterpret_cast<const bf16x8*>(
                    (char*)vt + (wv*64 + ct*16 + q)*128 + ((mm*64 + g*16) ^ swq));
            #pragma unroll
            for (int qt = 0; qt < 4; ++qt) {
                const bf16x8 pb = *reinterpret_cast<const bf16x8*>(
                    (char*)pt + qt*2048 + q*128 + ((mm*64 + g*16) ^ swq));
                #pragma unroll
                for (int ct = 0; ct < 4; ++ct)
                    acc[ct][qt] = __builtin_amdgcn_mfma_f32_16x16x32_bf16(vf[ct], pb, acc[ct][qt], 0, 0, 0);
            }
        }
    };

    bf16x8 kfA[4], kfB[4];
    loadK(mt0, kfA);
    int mt = mt0;
    for (; mt + 1 < mt1; mt += 2) {
        chunk(mt,   kfA, kfB, mt + 1);
        chunk(mt+1, kfB, kfA, (mt + 2 < mt1) ? mt + 2 : mt1 - 1);
    }
    if (mt < mt1) chunk(mt, kfA, kfB, mt);

    // write m,l for merge (wave owns q-block wv)
    if (g == 0) {
        float2 v; v.x = m; v.y = l;
        ml[(size_t)((half*4 + b)*N_POS) + qrow] = v;
    }

    // exchange l across waves (reuse f_s)
    __syncthreads();
    if (g == 0) f_s[wv*16 + q] = l;
    __syncthreads();
    float invl[4];
    #pragma unroll
    for (int qt = 0; qt < 4; ++qt) invl[qt] = 1.f / f_s[qt*16 + q];

    // write o_part: lane (g,q), acc[ct][qt] regs r -> c = wv*64+ct*16+4g+r, n = n0+qt*16+q
    char* obase = (char*)o_part + ((size_t)((half*4 + b)*N_POS) + n0)*512;
    #pragma unroll
    for (int qt = 0; qt < 4; ++qt) {
        char* orow = obase + (size_t)(qt*16 + q)*512 + (wv*64 + 4*g)*2;
        #pragma unroll
        for (int ct = 0; ct < 4; ++ct) {
            const uint32_t u0 = pk2bf(acc[ct][qt][0]*invl[qt], acc[ct][qt][1]*invl[qt]);
            const uint32_t u1 = pk2bf(acc[ct][qt][2]*invl[qt], acc[ct][qt][3]*invl[qt]);
            uint2 u; u.x = u0; u.y = u1;
            *reinterpret_cast<uint2*>(orow + ct*32) = u;
        }
    }
}

// ---------------- merge 3 splits + transpose + gamma*out + x ----------------
__global__ __launch_bounds__(256) void out_combine(
    const ushort* __restrict__ o_part, const float2* __restrict__ ml,
    const float* __restrict__ x, const float* __restrict__ gamma,
    float* __restrict__ out)
{
    __shared__ float t[64][65];
    __shared__ float w0s[64], w1s[64], w2s[64];
    const int tid = threadIdx.x;
    const int jj = tid & 63;
    const int ig = tid >> 6;
    const int nt = blockIdx.x;
    const int ct = blockIdx.y;
    const int b  = blockIdx.z;
    const int n0 = nt*64, c0 = ct*64;
    const float gm = gamma[0];

    if (tid < 64) {
        const float2 a0 = ml[(size_t)((0*4 + b)*N_POS) + n0 + tid];
        const float2 a1 = ml[(size_t)((1*4 + b)*N_POS) + n0 + tid];
        const float2 a2 = ml[(size_t)((2*4 + b)*N_POS) + n0 + tid];
        const float mm = fmaxf(a0.x, fmaxf(a1.x, a2.x));
        const float e0 = __expf(a0.x - mm) * a0.y;
        const float e1 = __expf(a1.x - mm) * a1.y;
        const float e2 = __expf(a2.x - mm) * a2.y;
        const float inv = 1.f / (e0 + e1 + e2);
        w0s[tid] = e0 * inv;
        w1s[tid] = e1 * inv;
        w2s[tid] = e2 * inv;
    }
    __syncthreads();

    #pragma unroll
    for (int ii = 0; ii < 8; ++ii) {
        const int flat = ii*256 + tid;
        const int nl = flat >> 5;
        const int cp = flat & 31;
        const size_t off = ((size_t)(b*N_POS) + n0 + nl)*C_DIM + c0 + 2*cp;
        const uint32_t d0 = *reinterpret_cast<const uint32_t*>(o_part + off);
        const uint32_t d1 = *reinterpret_cast<const uint32_t*>(o_part + (size_t)4*N_POS*C_DIM + off);
        const uint32_t d2 = *reinterpret_cast<const uint32_t*>(o_part + (size_t)8*N_POS*C_DIM + off);
        const float w0 = w0s[nl], w1 = w1s[nl], w2 = w2s[nl];
        t[nl][2*cp]   = w0*bf2f_lo(d0) + w1*bf2f_lo(d1) + w2*bf2f_lo(d2);
        t[nl][2*cp+1] = w0*bf2f_hi(d0) + w1*bf2f_hi(d1) + w2*bf2f_hi(d2);
    }
    __syncthreads();
    #pragma unroll
    for (int ii = 0; ii < 16; ++ii) {
        const int cl = ii*4 + ig;
        const size_t idx = ((size_t)(b*C_DIM) + c0 + cl)*N_POS + n0 + jj;
        out[idx] = gm * t[jj][cl] + x[idx];
    }
}

extern "C" void kernel_launch(void* const* d_in, const int* in_sizes, int n_in,
                              void* d_out, int out_size, void* d_ws, size_t ws_size,
                              hipStream_t stream)
{
    const float* x     = (const float*)d_in[0];
    const float* Wq    = (const float*)d_in[1];
    const float* bq    = (const float*)d_in[2];
    const float* Wk    = (const float*)d_in[3];
    const float* bk    = (const float*)d_in[4];
    const float* Wv    = (const float*)d_in[5];
    const float* bv    = (const float*)d_in[6];
    const float* gamma = (const float*)d_in[7];

    // ws layout (aliased): [0,24MB) = o_part (flash+) OVERLAPS xT_bf [0,8MB) (prep->qkv only)
    // then: ml 384KB | q_bf 1MB | k_bf 1MB | v_bf 8MB | W_bf 160KB | bias ~ total <35MB
    ushort* o_part = (ushort*)d_ws;
    ushort* xT_bf  = (ushort*)d_ws;                       // alias, dead before flash writes
    float2* ml     = (float2*)(o_part + (size_t)NSPLIT*4*N_POS*C_DIM);
    ushort* q_bf   = (ushort*)(ml + (size_t)NSPLIT*4*N_POS);
    ushort* k_bf   = q_bf + (size_t)4*N_POS*CQK_D;
    ushort* v_bf   = k_bf + (size_t)4*N_POS*CQK_D;
    ushort* W_bf   = v_bf + (size_t)4*C_DIM*N_POS;
    float*  bias_f = (float*)(W_bf + 320*C_DIM);
    float* out = (float*)d_out;

    prep<<<dim3(65,4,4), 256, 0, stream>>>(x, Wq, bq, Wk, bk, Wv, bv, xT_bf, W_bf, bias_f);
    qkv_gemm<<<dim3(64,4), 256, 0, stream>>>(xT_bf, W_bf, bias_f, q_bf, k_bf, v_bf);
    flash_mfma<<<dim3(64,NSPLIT,4), 256, 0, stream>>>(q_bf, k_bf, v_bf, o_part, ml);
    out_combine<<<dim3(64,4,4), 256, 0, stream>>>(o_part, ml, x, gamma, out);
}